// Round 1
// baseline (217.046 us; speedup 1.0000x reference)
//
#include <hip/hip_runtime.h>

#define N_NODES   50000
#define N_EDGES   800000
#define IN_DIM    100
#define HIDDEN    16
#define N_CLASSES 40

// ---------------------------------------------------------------------------
// y1 = X @ W1   [N,100] @ [100,16] -> [N,16]
// 64 rows per block; thread (r,q) computes output quad (row r, cols 4q..4q+3).
// W read from LDS as float4 (b128), X as broadcast b32 (2-way conflict = free).
// ---------------------------------------------------------------------------
#define GROWS 64
__global__ __launch_bounds__(256) void gemm_xw1(const float* __restrict__ X,
                                                const float* __restrict__ W,
                                                float* __restrict__ Y) {
    __shared__ __align__(16) float sX[GROWS * IN_DIM];   // 25.6 KB
    __shared__ __align__(16) float sW[IN_DIM * HIDDEN];  // 6.4 KB
    const int tid  = threadIdx.x;
    const int row0 = blockIdx.x * GROWS;
    const int nrows = min(GROWS, N_NODES - row0);

    const float4* W4 = (const float4*)W;
    float4* sW4 = (float4*)sW;
    for (int i = tid; i < (IN_DIM * HIDDEN) / 4; i += 256) sW4[i] = W4[i];

    const float4* X4 = (const float4*)(X + (size_t)row0 * IN_DIM); // 400B rows: 16B aligned
    float4* sX4 = (float4*)sX;
    const int nf4 = nrows * (IN_DIM / 4);
    for (int i = tid; i < nf4; i += 256) sX4[i] = X4[i];
    __syncthreads();

    const int r = tid >> 2;   // 0..63
    const int q = tid & 3;    // output quad
    if (r >= nrows) return;

    float4 acc = make_float4(0.f, 0.f, 0.f, 0.f);
    const float* xr = &sX[r * IN_DIM];
#pragma unroll
    for (int k = 0; k < IN_DIM; ++k) {
        const float xk = xr[k];
        const float4 w = *(const float4*)&sW[k * HIDDEN + q * 4];
        acc.x = fmaf(xk, w.x, acc.x);
        acc.y = fmaf(xk, w.y, acc.y);
        acc.z = fmaf(xk, w.z, acc.z);
        acc.w = fmaf(xk, w.w, acc.w);
    }
    *(float4*)&Y[(size_t)(row0 + r) * HIDDEN + q * 4] = acc;
}

// ---------------------------------------------------------------------------
// CSR build: histogram -> 2-kernel scan -> counting-sort scatter
// ---------------------------------------------------------------------------
__global__ __launch_bounds__(256) void hist_kernel(const int* __restrict__ dst,
                                                   int* __restrict__ cnt) {
    const int e = blockIdx.x * 256 + threadIdx.x;   // grid exact: 800000/256
    atomicAdd(&cnt[dst[e]], 1);
}

// Per-256-tile exclusive scan + tile sums.
__global__ __launch_bounds__(256) void scan1_kernel(const int* __restrict__ cnt,
                                                    int* __restrict__ tloc,
                                                    int* __restrict__ bsum) {
    const int tid = threadIdx.x;
    const int i = blockIdx.x * 256 + tid;
    const int v = (i < N_NODES) ? cnt[i] : 0;

    const int lane = tid & 63, w = tid >> 6;
    int x = v;  // inclusive scan within wave
#pragma unroll
    for (int d = 1; d < 64; d <<= 1) {
        int y = __shfl_up(x, d, 64);
        if (lane >= d) x += y;
    }
    __shared__ int wsum[4];
    if (lane == 63) wsum[w] = x;
    __syncthreads();
    int add = 0;
    for (int k = 0; k < w; ++k) add += wsum[k];
    const int incl = x + add;
    if (i < N_NODES) tloc[i] = incl - v;        // tile-local exclusive
    if (tid == 255) bsum[blockIdx.x] = incl;    // tile total
}

// Add tile-prefix (each block redundantly reduces bsum[0..b)); write offs+cursor.
__global__ __launch_bounds__(256) void scan2_kernel(const int* __restrict__ tloc,
                                                    const int* __restrict__ bsum,
                                                    int* __restrict__ offs,
                                                    int* __restrict__ curs) {
    const int tid = threadIdx.x;
    const int b = blockIdx.x;
    int s = 0;
    for (int k = tid; k < b; k += 256) s += bsum[k];
#pragma unroll
    for (int d = 32; d >= 1; d >>= 1) s += __shfl_down(s, d, 64);
    __shared__ int ws4[4];
    __shared__ int pref;
    if ((tid & 63) == 0) ws4[tid >> 6] = s;
    __syncthreads();
    if (tid == 0) pref = ws4[0] + ws4[1] + ws4[2] + ws4[3];
    __syncthreads();
    const int i = b * 256 + tid;
    if (i < N_NODES) {
        const int o = tloc[i] + pref;
        offs[i] = o;
        curs[i] = o;
    }
    if (b == 0 && tid == 0) offs[N_NODES] = N_EDGES;
}

// Counting-sort: one int-atomic per edge; pack (src, val) as int2.
__global__ __launch_bounds__(256) void scatter_kernel(const int* __restrict__ src,
                                                      const int* __restrict__ dst,
                                                      const float* __restrict__ val,
                                                      int* __restrict__ curs,
                                                      int2* __restrict__ sorted) {
    const int e = blockIdx.x * 256 + threadIdx.x;   // grid exact
    const int s = src[e];
    const int d = dst[e];
    const float v = val[e];
    const int p = atomicAdd(&curs[d], 1);
    sorted[p] = make_int2(s, __float_as_int(v));
}

// ---------------------------------------------------------------------------
// Atomic-free gather SpMM: 16 lanes own one node; walk its CSR segment.
// Z[n] = sum_e val_e * X[src_e];  optional ReLU applied to the OUTPUT row.
// ---------------------------------------------------------------------------
template <bool RELU_OUT>
__global__ __launch_bounds__(256) void gather_spmm(const int* __restrict__ offs,
                                                   const int2* __restrict__ sorted,
                                                   const float* __restrict__ X,
                                                   float* __restrict__ Z) {
    const int tid = threadIdx.x;
    const int n = blockIdx.x * 16 + (tid >> 4);   // grid exact: 50000/16
    const int j = tid & 15;
    const int beg = offs[n];
    const int end = offs[n + 1];

    float acc = 0.f;
    int p = beg;
    for (; p + 2 <= end; p += 2) {                 // 2-way MLP
        const int2 e0 = sorted[p];
        const int2 e1 = sorted[p + 1];
        const float x0 = X[(size_t)e0.x * HIDDEN + j];
        const float x1 = X[(size_t)e1.x * HIDDEN + j];
        acc = fmaf(__int_as_float(e0.y), x0, acc);
        acc = fmaf(__int_as_float(e1.y), x1, acc);
    }
    if (p < end) {
        const int2 e0 = sorted[p];
        const float x0 = X[(size_t)e0.x * HIDDEN + j];
        acc = fmaf(__int_as_float(e0.y), x0, acc);
    }
    if (RELU_OUT) acc = fmaxf(acc, 0.f);
    Z[(size_t)n * HIDDEN + j] = acc;
}

// ---------------------------------------------------------------------------
// out[n] = log_softmax(Z[n] @ W2).  64-thread blocks (782 blocks, ~3/CU),
// b128 LDS reads of W2, float4 stores.
// ---------------------------------------------------------------------------
__global__ __launch_bounds__(64) void out_logsoftmax(const float* __restrict__ Z,
                                                     const float* __restrict__ W2,
                                                     float* __restrict__ out) {
    __shared__ __align__(16) float sW[HIDDEN * N_CLASSES];  // 2.56 KB
    const int tid = threadIdx.x;
    const float4* W4 = (const float4*)W2;
    float4* sW4 = (float4*)sW;
    for (int i = tid; i < (HIDDEN * N_CLASSES) / 4; i += 64) sW4[i] = W4[i];
    __syncthreads();

    const int n = blockIdx.x * 64 + tid;
    if (n >= N_NODES) return;

    float z[HIDDEN];
    const float4* zp = (const float4*)(Z + (size_t)n * HIDDEN);
#pragma unroll
    for (int qz = 0; qz < 4; ++qz) {
        const float4 t = zp[qz];
        z[qz * 4 + 0] = t.x; z[qz * 4 + 1] = t.y;
        z[qz * 4 + 2] = t.z; z[qz * 4 + 3] = t.w;
    }

    float o[N_CLASSES];
#pragma unroll
    for (int c4 = 0; c4 < N_CLASSES / 4; ++c4) {
        float4 a = make_float4(0.f, 0.f, 0.f, 0.f);
#pragma unroll
        for (int k = 0; k < HIDDEN; ++k) {
            const float4 w = *(const float4*)&sW[k * N_CLASSES + c4 * 4];
            a.x = fmaf(z[k], w.x, a.x);
            a.y = fmaf(z[k], w.y, a.y);
            a.z = fmaf(z[k], w.z, a.z);
            a.w = fmaf(z[k], w.w, a.w);
        }
        o[c4 * 4 + 0] = a.x; o[c4 * 4 + 1] = a.y;
        o[c4 * 4 + 2] = a.z; o[c4 * 4 + 3] = a.w;
    }

    float m = -INFINITY;
#pragma unroll
    for (int c = 0; c < N_CLASSES; ++c) m = fmaxf(m, o[c]);
    float s = 0.f;
#pragma unroll
    for (int c = 0; c < N_CLASSES; ++c) s += __expf(o[c] - m);
    const float lse = m + __logf(s);

    float4* op4 = (float4*)(out + (size_t)n * N_CLASSES); // 160B rows: aligned
#pragma unroll
    for (int c4 = 0; c4 < N_CLASSES / 4; ++c4)
        op4[c4] = make_float4(o[c4 * 4 + 0] - lse, o[c4 * 4 + 1] - lse,
                              o[c4 * 4 + 2] - lse, o[c4 * 4 + 3] - lse);
}

extern "C" void kernel_launch(void* const* d_in, const int* in_sizes, int n_in,
                              void* d_out, int out_size, void* d_ws, size_t ws_size,
                              hipStream_t stream) {
    const float* features = (const float*)d_in[0];  // [50000,100]
    const int*   edge_src = (const int*)d_in[1];    // [800000]
    const int*   edge_dst = (const int*)d_in[2];    // [800000]
    const float* edge_val = (const float*)d_in[3];  // [800000]
    const float* W1       = (const float*)d_in[4];  // [100,16]
    const float* W2       = (const float*)d_in[5];  // [16,40]
    float*       out      = (float*)d_out;          // [50000,40]

    char* base = (char*)d_ws;
    const size_t HNB = (size_t)N_NODES * HIDDEN * sizeof(float);   // 3.2 MB
    float* y1   = (float*)(base);                    // y1; reused as z2
    float* z1   = (float*)(base + HNB);              // relu(A@y1)
    int*   cnt  = (int*)  (base + 2 * HNB);                 // 200 KB
    int*   tloc = (int*)  (base + 2 * HNB + 256 * 1024);    // 200 KB
    int*   bsum = (int*)  (base + 2 * HNB + 512 * 1024);    // 784 B
    int*   offs = (int*)  (base + 2 * HNB + 768 * 1024);    // 200 KB + 4
    int*   curs = (int*)  (base + 2 * HNB + 1280 * 1024);   // 200 KB
    int2*  sorted = (int2*)(base + 2 * HNB + 2048 * 1024);  // 6.4 MB
    float* z2   = y1;

    const int SCAN_BLOCKS = (N_NODES + 255) / 256;          // 196

    // --- CSR build (amortized over both spmms) ---
    hipMemsetAsync(cnt, 0, (size_t)N_NODES * sizeof(int), stream);
    hist_kernel<<<N_EDGES / 256, 256, 0, stream>>>(edge_dst, cnt);
    scan1_kernel<<<SCAN_BLOCKS, 256, 0, stream>>>(cnt, tloc, bsum);
    scan2_kernel<<<SCAN_BLOCKS, 256, 0, stream>>>(tloc, bsum, offs, curs);
    scatter_kernel<<<N_EDGES / 256, 256, 0, stream>>>(edge_src, edge_dst, edge_val,
                                                      curs, sorted);

    // --- dense pipeline ---
    gemm_xw1<<<(N_NODES + GROWS - 1) / GROWS, 256, 0, stream>>>(features, W1, y1);

    // z1 = relu(A @ y1)   (relu folded into the write)
    gather_spmm<true><<<N_NODES / 16, 256, 0, stream>>>(offs, sorted, y1, z1);

    // z2 = A @ z1
    gather_spmm<false><<<N_NODES / 16, 256, 0, stream>>>(offs, sorted, z1, z2);

    // out = log_softmax(z2 @ W2)
    out_logsoftmax<<<(N_NODES + 63) / 64, 64, 0, stream>>>(z2, W2, out);
}